// Round 1
// baseline (2719.373 us; speedup 1.0000x reference)
//
#include <hip/hip_runtime.h>
#include <math.h>

#define N_NODES 600000
#define N_EDGES 2400000
#define HD 64
#define F_IN 128
#define LEADS 12
#define NUM_GRAPHS 50000
#define OUT_DIM 32

// ---------------- degree / norm ----------------
__global__ __launch_bounds__(256) void k_deg_init(float* __restrict__ deg) {
    int i = blockIdx.x * 256 + threadIdx.x;
    if (i < N_NODES) deg[i] = 1.0f;  // self-loop
}

__global__ __launch_bounds__(256) void k_deg_count(const int* __restrict__ dst,
                                                   float* __restrict__ deg) {
    int e = blockIdx.x * 256 + threadIdx.x;
    if (e < N_EDGES) unsafeAtomicAdd(&deg[dst[e]], 1.0f);
}

__global__ __launch_bounds__(256) void k_dinv(float* __restrict__ deg) {
    int i = blockIdx.x * 256 + threadIdx.x;
    if (i < N_NODES) deg[i] = rsqrtf(deg[i]);  // deg >= 1 always
}

// ---------------- GEMM: out-col = lane, W col in regs, x rows broadcast from LDS ----
// Computes t'[r][c] = dinv[r] * sum_k act(in[r][k]) * W[k][c], dual-stores to tout & aggout.
// ACT: in-value -> relu(dinv[row]*v + bprev[channel])   (fused epilogue of previous layer)
template <int K, bool ACT>
__global__ __launch_bounds__(256) void k_gemm(const float* __restrict__ in,
                                              const float* __restrict__ W,
                                              const float* __restrict__ bprev,
                                              const float* __restrict__ dinv,
                                              float* __restrict__ tout,
                                              float* __restrict__ aggout) {
    __shared__ float lds_x[32 * K];
    const int t = threadIdx.x;
    const int lane = t & 63;
    const int wid = t >> 6;
    const int r0 = blockIdx.x * 32;

    // W column -> registers (fully unrolled so it stays in VGPRs)
    float wcol[K];
#pragma unroll
    for (int k = 0; k < K; ++k) wcol[k] = W[k * HD + lane];

    // cooperative staging of 32 rows, float4, coalesced
    constexpr int NF4 = 32 * K / 4;
#pragma unroll
    for (int i = 0; i < NF4 / 256; ++i) {
        int f = (t + i * 256) * 4;
        int rl = f / K;
        int k0 = f % K;
        float4 v = *(const float4*)(in + (size_t)(r0 + rl) * K + k0);
        if constexpr (ACT) {
            float di = dinv[r0 + rl];
            float4 b4 = *(const float4*)(bprev + k0);
            v.x = fmaxf(di * v.x + b4.x, 0.0f);
            v.y = fmaxf(di * v.y + b4.y, 0.0f);
            v.z = fmaxf(di * v.z + b4.z, 0.0f);
            v.w = fmaxf(di * v.w + b4.w, 0.0f);
        }
        *(float4*)(lds_x + f) = v;
    }
    __syncthreads();

    float acc[8];
#pragma unroll
    for (int rr = 0; rr < 8; ++rr) acc[rr] = 0.0f;

    const float4* lx4 = (const float4*)lds_x;
#pragma unroll
    for (int k4 = 0; k4 < K / 4; ++k4) {
#pragma unroll
        for (int rr = 0; rr < 8; ++rr) {
            float4 xb = lx4[(wid * 8 + rr) * (K / 4) + k4];  // same addr across lanes -> broadcast
            acc[rr] = fmaf(xb.x, wcol[4 * k4 + 0], acc[rr]);
            acc[rr] = fmaf(xb.y, wcol[4 * k4 + 1], acc[rr]);
            acc[rr] = fmaf(xb.z, wcol[4 * k4 + 2], acc[rr]);
            acc[rr] = fmaf(xb.w, wcol[4 * k4 + 3], acc[rr]);
        }
    }

#pragma unroll
    for (int rr = 0; rr < 8; ++rr) {
        int grow = r0 + wid * 8 + rr;
        float tv = acc[rr] * dinv[grow];  // pre-scale by dinv[src]
        tout[(size_t)grow * HD + lane] = tv;
        aggout[(size_t)grow * HD + lane] = tv;  // self-loop init
    }
}

// ---------------- edge scatter: one wave per edge, lane = channel ----------------
__global__ __launch_bounds__(256) void k_scatter(const int* __restrict__ src,
                                                 const int* __restrict__ dst,
                                                 const float* __restrict__ tprime,
                                                 float* __restrict__ agg) {
    int e = (blockIdx.x * 256 + threadIdx.x) >> 6;
    int lane = threadIdx.x & 63;
    if (e < N_EDGES) {
        int s = src[e];
        int d = dst[e];
        float v = tprime[(size_t)s * HD + lane];
        unsafeAtomicAdd(&agg[(size_t)d * HD + lane], v);
    }
}

// ---------------- fused epilogue + lead attention + pool + linear ----------------
__global__ __launch_bounds__(256) void k_attn(const float* __restrict__ agg3,
                                              const float* __restrict__ dinv,
                                              const float* __restrict__ b3,
                                              const float* __restrict__ Wa,
                                              const float* __restrict__ vvec,
                                              const float* __restrict__ Wl,
                                              const float* __restrict__ bl,
                                              float* __restrict__ out,
                                              float* __restrict__ lw) {
    __shared__ float lds_Wl[128 * 32];
    __shared__ float lds_h[4][LEADS * 64];
    __shared__ float lds_p[4][128];
    const int t = threadIdx.x;
    const int lane = t & 63;
    const int wid = t >> 6;

#pragma unroll
    for (int i = 0; i < 16; ++i) lds_Wl[t + i * 256] = Wl[t + i * 256];

    float wa[64];
#pragma unroll
    for (int k = 0; k < 64; ++k) wa[k] = Wa[k * 64 + lane];
    float vl = vvec[lane];
    float bias3 = b3[lane];
    __syncthreads();

    const int g = blockIdx.x * 4 + wid;

    // h3 rows: fused relu(dinv*agg3 + b3)
    float hv[LEADS];
#pragma unroll
    for (int r = 0; r < LEADS; ++r) {
        int node = g * LEADS + r;
        float av = agg3[(size_t)node * 64 + lane];
        hv[r] = fmaxf(dinv[node] * av + bias3, 0.0f);
        lds_h[wid][r * 64 + lane] = hv[r];
    }

    // scores: s[r] = sum_c tanh(sum_k h[r][k]*Wa[k][c]) * v[c]
    float s_[LEADS];
#pragma unroll
    for (int r = 0; r < LEADS; ++r) {
        float acc = 0.0f;
        const float4* h4 = (const float4*)&lds_h[wid][r * 64];
#pragma unroll
        for (int k4 = 0; k4 < 16; ++k4) {
            float4 hb = h4[k4];  // broadcast read
            acc = fmaf(hb.x, wa[4 * k4 + 0], acc);
            acc = fmaf(hb.y, wa[4 * k4 + 1], acc);
            acc = fmaf(hb.z, wa[4 * k4 + 2], acc);
            acc = fmaf(hb.w, wa[4 * k4 + 3], acc);
        }
        float sc = tanhf(acc) * vl;
#pragma unroll
        for (int off = 32; off >= 1; off >>= 1) sc += __shfl_xor(sc, off);
        s_[r] = sc;  // replicated on all lanes
    }

    // softmax over the 12 leads
    float m = s_[0];
#pragma unroll
    for (int r = 1; r < LEADS; ++r) m = fmaxf(m, s_[r]);
    float wgt[LEADS];
    float sum = 0.0f;
#pragma unroll
    for (int r = 0; r < LEADS; ++r) {
        wgt[r] = expf(s_[r] - m);
        sum += wgt[r];
    }
    float inv = 1.0f / sum;

    // lweights output (lane r holds weight r via cndmask chain)
    float tmp = wgt[0] * inv;
#pragma unroll
    for (int r = 1; r < LEADS; ++r) tmp = (lane == r) ? wgt[r] * inv : tmp;
    if (lane < LEADS) lw[g * LEADS + lane] = tmp;

    // weighted max + mean pool
    float gmax = -1e30f, gsum = 0.0f;
#pragma unroll
    for (int r = 0; r < LEADS; ++r) {
        float wh = hv[r] * (wgt[r] * inv);
        gmax = fmaxf(gmax, wh);
        gsum += wh;
    }
    lds_p[wid][lane] = gmax;
    lds_p[wid][64 + lane] = gsum * (1.0f / 12.0f);

    // final linear: pooled(128) @ Wl(128x32), split K across lane halves
    int o = lane & 31, half = lane >> 5;
    float acc2 = 0.0f;
#pragma unroll
    for (int k = 0; k < 64; ++k) {
        int kk = half * 64 + k;
        acc2 = fmaf(lds_p[wid][kk], lds_Wl[kk * 32 + o], acc2);
    }
    acc2 += __shfl_xor(acc2, 32);
    if (lane < 32) out[g * 32 + lane] = fmaxf(acc2 + bl[lane], 0.0f);
}

// ---------------- launch ----------------
extern "C" void kernel_launch(void* const* d_in, const int* in_sizes, int n_in,
                              void* d_out, int out_size, void* d_ws, size_t ws_size,
                              hipStream_t stream) {
    const float* x  = (const float*)d_in[0];
    const int* ei   = (const int*)d_in[1];
    const int* src  = ei;             // edge_index[0]
    const int* dst  = ei + N_EDGES;   // edge_index[1]
    const float* W1 = (const float*)d_in[3];
    const float* b1 = (const float*)d_in[4];
    const float* W2 = (const float*)d_in[5];
    const float* b2 = (const float*)d_in[6];
    const float* W3 = (const float*)d_in[7];
    const float* b3 = (const float*)d_in[8];
    const float* Wa = (const float*)d_in[9];
    const float* vv = (const float*)d_in[10];
    const float* Wl = (const float*)d_in[11];
    const float* bl = (const float*)d_in[12];

    float* out = (float*)d_out;                  // [G,32]
    float* lw  = out + (size_t)NUM_GRAPHS * 32;  // [G,12]

    float* dinv = (float*)d_ws;                    // N floats (deg -> dinv in place)
    float* A = dinv + N_NODES;                     // N*64
    float* B = A + (size_t)N_NODES * HD;           // N*64
    float* C = B + (size_t)N_NODES * HD;           // N*64

    k_deg_init<<<(N_NODES + 255) / 256, 256, 0, stream>>>(dinv);
    k_deg_count<<<(N_EDGES + 255) / 256, 256, 0, stream>>>(dst, dinv);
    k_dinv<<<(N_NODES + 255) / 256, 256, 0, stream>>>(dinv);

    // layer 1: t1=A, agg1=B
    k_gemm<128, false><<<N_NODES / 32, 256, 0, stream>>>(x, W1, nullptr, dinv, A, B);
    k_scatter<<<N_EDGES / 4, 256, 0, stream>>>(src, dst, A, B);
    // layer 2: in=B(+b1 act), t2=C, agg2=A
    k_gemm<64, true><<<N_NODES / 32, 256, 0, stream>>>(B, W2, b1, dinv, C, A);
    k_scatter<<<N_EDGES / 4, 256, 0, stream>>>(src, dst, C, A);
    // layer 3: in=A(+b2 act), t3=B, agg3=C
    k_gemm<64, true><<<N_NODES / 32, 256, 0, stream>>>(A, W3, b2, dinv, B, C);
    k_scatter<<<N_EDGES / 4, 256, 0, stream>>>(src, dst, B, C);
    // epilogue(b3) + attention + pool + linear
    k_attn<<<NUM_GRAPHS / 4, 256, 0, stream>>>(C, dinv, b3, Wa, vv, Wl, bl, out, lw);
}

// Round 2
// 1949.318 us; speedup vs baseline: 1.3950x; 1.3950x over previous
//
#include <hip/hip_runtime.h>
#include <math.h>

#define N_NODES 600000
#define N_EDGES 2400000
#define HD 64
#define F_IN 128
#define LEADS 12
#define NUM_GRAPHS 50000
#define OUT_DIM 32
#define SCAN_BLOCKS 586  // ceil(600000/1024)

// ---------------- CSR build ----------------
__global__ __launch_bounds__(256) void k_zero(int* __restrict__ cnt) {
    int i = blockIdx.x * 256 + threadIdx.x;
    if (i < N_NODES) cnt[i] = 0;
}

__global__ __launch_bounds__(256) void k_hist(const int* __restrict__ dst,
                                              int* __restrict__ cnt) {
    int e = blockIdx.x * 256 + threadIdx.x;
    if (e < N_EDGES) atomicAdd(&cnt[dst[e]], 1);
}

__global__ __launch_bounds__(256) void k_dinv(const int* __restrict__ cnt,
                                              float* __restrict__ dinv) {
    int i = blockIdx.x * 256 + threadIdx.x;
    if (i < N_NODES) dinv[i] = rsqrtf((float)(cnt[i] + 1));  // +1 self-loop
}

// phase 1: per-block (1024 elements) exclusive scan, write block sums
__global__ __launch_bounds__(256) void k_scan1(const int* __restrict__ cnt,
                                               int* __restrict__ offs,
                                               int* __restrict__ bsum) {
    __shared__ int lds[256];
    int t = threadIdx.x;
    int base = blockIdx.x * 1024 + t * 4;
    int v[4];
#pragma unroll
    for (int j = 0; j < 4; ++j) v[j] = (base + j < N_NODES) ? cnt[base + j] : 0;
    int s = v[0] + v[1] + v[2] + v[3];
    lds[t] = s;
    __syncthreads();
    int val = s;
    for (int off = 1; off < 256; off <<= 1) {
        int other = (t >= off) ? lds[t - off] : 0;
        __syncthreads();
        val += other;
        lds[t] = val;
        __syncthreads();
    }
    if (t == 255) bsum[blockIdx.x] = val;
    int run = val - s;  // exclusive prefix for this thread's chunk
#pragma unroll
    for (int j = 0; j < 4; ++j) {
        if (base + j < N_NODES) offs[base + j] = run;
        run += v[j];
    }
}

// phase 2: exclusive scan of the 586 block sums (single block)
__global__ __launch_bounds__(256) void k_scan2(int* __restrict__ bsum) {
    __shared__ int lds[SCAN_BLOCKS];
    for (int i = threadIdx.x; i < SCAN_BLOCKS; i += 256) lds[i] = bsum[i];
    __syncthreads();
    if (threadIdx.x == 0) {
        int run = 0;
        for (int i = 0; i < SCAN_BLOCKS; ++i) {
            int c = lds[i];
            lds[i] = run;
            run += c;
        }
    }
    __syncthreads();
    for (int i = threadIdx.x; i < SCAN_BLOCKS; i += 256) bsum[i] = lds[i];
}

// phase 3: add block base; also init cursor
__global__ __launch_bounds__(256) void k_scan3(int* __restrict__ offs,
                                               const int* __restrict__ bsum,
                                               int* __restrict__ cursor) {
    int i = blockIdx.x * 256 + threadIdx.x;
    if (i < N_NODES) {
        int o = offs[i] + bsum[i >> 10];
        offs[i] = o;
        cursor[i] = o;
    }
}

__global__ __launch_bounds__(256) void k_fill(const int* __restrict__ src,
                                              const int* __restrict__ dst,
                                              int* __restrict__ cursor,
                                              int* __restrict__ eidx) {
    int e = blockIdx.x * 256 + threadIdx.x;
    if (e < N_EDGES) {
        int p = atomicAdd(&cursor[dst[e]], 1);
        eidx[p] = src[e];
    }
}

// ---------------- GEMM: t'[r][c] = dinv[r] * sum_k in[r][k] * W[k][c] ----------------
template <int K>
__global__ __launch_bounds__(256) void k_gemm(const float* __restrict__ in,
                                              const float* __restrict__ W,
                                              const float* __restrict__ dinv,
                                              float* __restrict__ tout) {
    __shared__ float lds_x[32 * K];
    const int t = threadIdx.x;
    const int lane = t & 63;
    const int wid = t >> 6;
    const int r0 = blockIdx.x * 32;

    float wcol[K];
#pragma unroll
    for (int k = 0; k < K; ++k) wcol[k] = W[k * HD + lane];

    constexpr int NF4 = 32 * K / 4;
#pragma unroll
    for (int i = 0; i < NF4 / 256; ++i) {
        int f = (t + i * 256) * 4;
        *(float4*)(lds_x + f) = *(const float4*)(in + (size_t)r0 * K + f);
    }
    __syncthreads();

    float acc[8];
#pragma unroll
    for (int rr = 0; rr < 8; ++rr) acc[rr] = 0.0f;

    const float4* lx4 = (const float4*)lds_x;
#pragma unroll
    for (int k4 = 0; k4 < K / 4; ++k4) {
#pragma unroll
        for (int rr = 0; rr < 8; ++rr) {
            float4 xb = lx4[(wid * 8 + rr) * (K / 4) + k4];  // broadcast read
            acc[rr] = fmaf(xb.x, wcol[4 * k4 + 0], acc[rr]);
            acc[rr] = fmaf(xb.y, wcol[4 * k4 + 1], acc[rr]);
            acc[rr] = fmaf(xb.z, wcol[4 * k4 + 2], acc[rr]);
            acc[rr] = fmaf(xb.w, wcol[4 * k4 + 3], acc[rr]);
        }
    }

#pragma unroll
    for (int rr = 0; rr < 8; ++rr) {
        int grow = r0 + wid * 8 + rr;
        tout[(size_t)grow * HD + lane] = acc[rr] * dinv[grow];
    }
}

// ---------------- gather + epilogue: h[i] = relu(dinv[i]*(t[i]+sum t[src]) + b) ------
__global__ __launch_bounds__(256) void k_gather(const float* __restrict__ tp,
                                                const int* __restrict__ eidx,
                                                const int* __restrict__ offs,
                                                const int* __restrict__ cnt,
                                                const float* __restrict__ dinv,
                                                const float* __restrict__ bias,
                                                float* __restrict__ h) {
    int node = (blockIdx.x * 256 + threadIdx.x) >> 6;
    int lane = threadIdx.x & 63;
    if (node >= N_NODES) return;
    float a0 = tp[(size_t)node * HD + lane];  // self-loop
    float a1 = 0.0f;
    int start = offs[node];   // wave-uniform -> s_load
    int c = cnt[node];
    int j = 0;
    for (; j + 1 < c; j += 2) {
        int s0 = eidx[start + j];      // wave-uniform
        int s1 = eidx[start + j + 1];
        float v0 = tp[(size_t)s0 * HD + lane];
        float v1 = tp[(size_t)s1 * HD + lane];
        a0 += v0;
        a1 += v1;
    }
    if (j < c) a0 += tp[(size_t)eidx[start + j] * HD + lane];
    h[(size_t)node * HD + lane] = fmaxf(fmaf(dinv[node], a0 + a1, bias[lane]), 0.0f);
}

// ---------------- lead attention + pool + linear ----------------
__global__ __launch_bounds__(256) void k_attn(const float* __restrict__ h3,
                                              const float* __restrict__ Wa,
                                              const float* __restrict__ vvec,
                                              const float* __restrict__ Wl,
                                              const float* __restrict__ bl,
                                              float* __restrict__ out,
                                              float* __restrict__ lw) {
    __shared__ float lds_Wl[128 * 32];
    __shared__ float lds_h[4][LEADS * 64];
    __shared__ float lds_p[4][128];
    const int t = threadIdx.x;
    const int lane = t & 63;
    const int wid = t >> 6;

#pragma unroll
    for (int i = 0; i < 16; ++i) lds_Wl[t + i * 256] = Wl[t + i * 256];

    float wa[64];
#pragma unroll
    for (int k = 0; k < 64; ++k) wa[k] = Wa[k * 64 + lane];
    float vl = vvec[lane];
    __syncthreads();

    const int g = blockIdx.x * 4 + wid;

    float hv[LEADS];
#pragma unroll
    for (int r = 0; r < LEADS; ++r) {
        hv[r] = h3[(size_t)(g * LEADS + r) * 64 + lane];
        lds_h[wid][r * 64 + lane] = hv[r];
    }

    float s_[LEADS];
#pragma unroll
    for (int r = 0; r < LEADS; ++r) {
        float acc = 0.0f;
        const float4* h4 = (const float4*)&lds_h[wid][r * 64];
#pragma unroll
        for (int k4 = 0; k4 < 16; ++k4) {
            float4 hb = h4[k4];  // broadcast read
            acc = fmaf(hb.x, wa[4 * k4 + 0], acc);
            acc = fmaf(hb.y, wa[4 * k4 + 1], acc);
            acc = fmaf(hb.z, wa[4 * k4 + 2], acc);
            acc = fmaf(hb.w, wa[4 * k4 + 3], acc);
        }
        float sc = tanhf(acc) * vl;
#pragma unroll
        for (int off = 32; off >= 1; off >>= 1) sc += __shfl_xor(sc, off);
        s_[r] = sc;
    }

    float m = s_[0];
#pragma unroll
    for (int r = 1; r < LEADS; ++r) m = fmaxf(m, s_[r]);
    float wgt[LEADS];
    float sum = 0.0f;
#pragma unroll
    for (int r = 0; r < LEADS; ++r) {
        wgt[r] = expf(s_[r] - m);
        sum += wgt[r];
    }
    float inv = 1.0f / sum;

    float tmp = wgt[0] * inv;
#pragma unroll
    for (int r = 1; r < LEADS; ++r) tmp = (lane == r) ? wgt[r] * inv : tmp;
    if (lane < LEADS) lw[g * LEADS + lane] = tmp;

    float gmax = -1e30f, gsum = 0.0f;
#pragma unroll
    for (int r = 0; r < LEADS; ++r) {
        float wh = hv[r] * (wgt[r] * inv);
        gmax = fmaxf(gmax, wh);
        gsum += wh;
    }
    lds_p[wid][lane] = gmax;
    lds_p[wid][64 + lane] = gsum * (1.0f / 12.0f);

    int o = lane & 31, half = lane >> 5;
    float acc2 = 0.0f;
#pragma unroll
    for (int k = 0; k < 64; ++k) {
        int kk = half * 64 + k;
        acc2 = fmaf(lds_p[wid][kk], lds_Wl[kk * 32 + o], acc2);
    }
    acc2 += __shfl_xor(acc2, 32);
    if (lane < 32) out[g * 32 + lane] = fmaxf(acc2 + bl[lane], 0.0f);
}

// ---------------- launch ----------------
extern "C" void kernel_launch(void* const* d_in, const int* in_sizes, int n_in,
                              void* d_out, int out_size, void* d_ws, size_t ws_size,
                              hipStream_t stream) {
    const float* x  = (const float*)d_in[0];
    const int* ei   = (const int*)d_in[1];
    const int* src  = ei;
    const int* dst  = ei + N_EDGES;
    const float* W1 = (const float*)d_in[3];
    const float* b1 = (const float*)d_in[4];
    const float* W2 = (const float*)d_in[5];
    const float* b2 = (const float*)d_in[6];
    const float* W3 = (const float*)d_in[7];
    const float* b3 = (const float*)d_in[8];
    const float* Wa = (const float*)d_in[9];
    const float* vv = (const float*)d_in[10];
    const float* Wl = (const float*)d_in[11];
    const float* bl = (const float*)d_in[12];

    float* out = (float*)d_out;
    float* lw  = out + (size_t)NUM_GRAPHS * 32;

    // workspace layout
    float* dinv = (float*)d_ws;                       // N f32
    int* cnt    = (int*)(dinv + N_NODES);             // N
    int* offs   = cnt + N_NODES;                      // N
    int* cursor = offs + N_NODES;                     // N
    int* bsum   = cursor + N_NODES;                   // 1024
    int* eidx   = bsum + 1024;                        // E
    float* T    = (float*)(eidx + N_EDGES);           // N*64
    float* Hb   = T + (size_t)N_NODES * HD;           // N*64

    const int gN = (N_NODES + 255) / 256;
    const int gE = (N_EDGES + 255) / 256;

    // CSR build + norm
    k_zero<<<gN, 256, 0, stream>>>(cnt);
    k_hist<<<gE, 256, 0, stream>>>(dst, cnt);
    k_dinv<<<gN, 256, 0, stream>>>(cnt, dinv);
    k_scan1<<<SCAN_BLOCKS, 256, 0, stream>>>(cnt, offs, bsum);
    k_scan2<<<1, 256, 0, stream>>>(bsum);
    k_scan3<<<gN, 256, 0, stream>>>(offs, bsum, cursor);
    k_fill<<<gE, 256, 0, stream>>>(src, dst, cursor, eidx);

    // layer 1
    k_gemm<128><<<N_NODES / 32, 256, 0, stream>>>(x, W1, dinv, T);
    k_gather<<<(N_NODES * 64) / 256, 256, 0, stream>>>(T, eidx, offs, cnt, dinv, b1, Hb);
    // layer 2
    k_gemm<64><<<N_NODES / 32, 256, 0, stream>>>(Hb, W2, dinv, T);
    k_gather<<<(N_NODES * 64) / 256, 256, 0, stream>>>(T, eidx, offs, cnt, dinv, b2, Hb);
    // layer 3
    k_gemm<64><<<N_NODES / 32, 256, 0, stream>>>(Hb, W3, dinv, T);
    k_gather<<<(N_NODES * 64) / 256, 256, 0, stream>>>(T, eidx, offs, cnt, dinv, b3, Hb);
    // attention + pool + linear
    k_attn<<<NUM_GRAPHS / 4, 256, 0, stream>>>(Hb, Wa, vv, Wl, bl, out, lw);
}

// Round 3
// 1577.500 us; speedup vs baseline: 1.7238x; 1.2357x over previous
//
#include <hip/hip_runtime.h>
#include <math.h>

#define N_NODES 600000
#define N_EDGES 2400000
#define HD 64
#define F_IN 128
#define LEADS 12
#define NUM_GRAPHS 50000
#define OUT_DIM 32
#define SCAN_BLOCKS 586  // ceil(600000/1024)

// ---------------- CSR build ----------------
__global__ __launch_bounds__(256) void k_zero(int* __restrict__ cnt) {
    int i = blockIdx.x * 256 + threadIdx.x;
    if (i < N_NODES) cnt[i] = 0;
}

__global__ __launch_bounds__(256) void k_hist(const int* __restrict__ dst,
                                              int* __restrict__ cnt) {
    int e = blockIdx.x * 256 + threadIdx.x;
    if (e < N_EDGES) atomicAdd(&cnt[dst[e]], 1);
}

__global__ __launch_bounds__(256) void k_dinv(const int* __restrict__ cnt,
                                              float* __restrict__ dinv) {
    int i = blockIdx.x * 256 + threadIdx.x;
    if (i < N_NODES) dinv[i] = rsqrtf((float)(cnt[i] + 1));  // +1 self-loop
}

__global__ __launch_bounds__(256) void k_scan1(const int* __restrict__ cnt,
                                               int* __restrict__ offs,
                                               int* __restrict__ bsum) {
    __shared__ int lds[256];
    int t = threadIdx.x;
    int base = blockIdx.x * 1024 + t * 4;
    int v[4];
#pragma unroll
    for (int j = 0; j < 4; ++j) v[j] = (base + j < N_NODES) ? cnt[base + j] : 0;
    int s = v[0] + v[1] + v[2] + v[3];
    lds[t] = s;
    __syncthreads();
    int val = s;
    for (int off = 1; off < 256; off <<= 1) {
        int other = (t >= off) ? lds[t - off] : 0;
        __syncthreads();
        val += other;
        lds[t] = val;
        __syncthreads();
    }
    if (t == 255) bsum[blockIdx.x] = val;
    int run = val - s;
#pragma unroll
    for (int j = 0; j < 4; ++j) {
        if (base + j < N_NODES) offs[base + j] = run;
        run += v[j];
    }
}

__global__ __launch_bounds__(256) void k_scan2(int* __restrict__ bsum) {
    __shared__ int lds[SCAN_BLOCKS];
    for (int i = threadIdx.x; i < SCAN_BLOCKS; i += 256) lds[i] = bsum[i];
    __syncthreads();
    if (threadIdx.x == 0) {
        int run = 0;
        for (int i = 0; i < SCAN_BLOCKS; ++i) {
            int c = lds[i];
            lds[i] = run;
            run += c;
        }
    }
    __syncthreads();
    for (int i = threadIdx.x; i < SCAN_BLOCKS; i += 256) bsum[i] = lds[i];
}

__global__ __launch_bounds__(256) void k_scan3(int* __restrict__ offs,
                                               const int* __restrict__ bsum,
                                               int* __restrict__ cursor) {
    int i = blockIdx.x * 256 + threadIdx.x;
    if (i < N_NODES) {
        int o = offs[i] + bsum[i >> 10];
        offs[i] = o;
        cursor[i] = o;
    }
}

__global__ __launch_bounds__(256) void k_fill(const int* __restrict__ src,
                                              const int* __restrict__ dst,
                                              int* __restrict__ cursor,
                                              int* __restrict__ eidx) {
    int e = blockIdx.x * 256 + threadIdx.x;
    if (e < N_EDGES) {
        int p = atomicAdd(&cursor[dst[e]], 1);
        eidx[p] = src[e];
    }
}

// ---------------- GEMM: lane=row, scalar W, 16 cols per wave --------------------
// t'[r][c] = dinv[r] * sum_k in[r][k] * W[k][c].  64 rows per block, wave w -> cols [16w,16w+16)
template <int K>
__global__ __launch_bounds__(256) void k_gemm(const float* __restrict__ in,
                                              const float* __restrict__ W,
                                              const float* __restrict__ dinv,
                                              float* __restrict__ tout) {
    __shared__ float lx[64 * (K + 1)];
    const int t = threadIdx.x;
    const int lane = t & 63;
    const int r0 = blockIdx.x * 64;

    // stage 64 rows, coalesced float4, scalar writes into padded LDS (stride K+1)
#pragma unroll
    for (int i = 0; i < K / 16; ++i) {
        int f = (t + i * 256) * 4;
        int r = f / K, k = f % K;
        float4 v = *(const float4*)(in + (size_t)(r0 + r) * K + k);
        float* p = &lx[r * (K + 1) + k];
        p[0] = v.x; p[1] = v.y; p[2] = v.z; p[3] = v.w;
    }
    __syncthreads();

    // wave-uniform column base so W loads become s_load
    const int c0 = __builtin_amdgcn_readfirstlane((t >> 6) * 16);
    const float* Wp = W + c0;

    float acc[16];
#pragma unroll
    for (int cc = 0; cc < 16; ++cc) acc[cc] = 0.0f;

#pragma unroll
    for (int k = 0; k < K; ++k) {
        float xk = lx[lane * (K + 1) + k];  // stride K+1 -> conflict-free
#pragma unroll
        for (int cc = 0; cc < 16; ++cc)
            acc[cc] = fmaf(xk, Wp[k * HD + cc], acc[cc]);  // SGPR operand
    }

    float di = dinv[r0 + lane];
#pragma unroll
    for (int cc = 0; cc < 16; ++cc) acc[cc] *= di;

    __syncthreads();  // reuse lx as transpose buffer (stride 65)
#pragma unroll
    for (int cc = 0; cc < 16; ++cc) lx[lane * 65 + c0 + cc] = acc[cc];
    __syncthreads();

    const int w = t >> 6;
#pragma unroll
    for (int i = 0; i < 16; ++i) {
        int r = i * 4 + w;
        tout[(size_t)(r0 + r) * HD + lane] = lx[r * 65 + lane];
    }
}

// ---------------- gather: 4 nodes/wave, 16 lanes x float4 each --------------------
__global__ __launch_bounds__(256) void k_gather(const float* __restrict__ tp,
                                                const int* __restrict__ eidx,
                                                const int* __restrict__ offs,
                                                const int* __restrict__ cnt,
                                                const float* __restrict__ dinv,
                                                const float* __restrict__ bias,
                                                float* __restrict__ h) {
    const int wave = (blockIdx.x * 256 + threadIdx.x) >> 6;
    const int lane = threadIdx.x & 63;
    const int grp = lane >> 4, sl = lane & 15;
    const int node = wave * 4 + grp;

    const float4* tp4 = (const float4*)tp;
    float4 a0 = tp4[(size_t)node * 16 + sl];  // self-loop
    float4 a1 = {0.0f, 0.0f, 0.0f, 0.0f};

    const int start = offs[node];
    const int c = cnt[node];

    // wave-uniform trip count = max degree in wave
    int cm = c;
#pragma unroll
    for (int off = 32; off >= 1; off >>= 1) cm = max(cm, __shfl_xor(cm, off));

    int j = 0;
    for (; j + 1 < cm; j += 2) {
        if (j < c) {
            int s0 = eidx[start + j];
            float4 v = tp4[(size_t)s0 * 16 + sl];
            a0.x += v.x; a0.y += v.y; a0.z += v.z; a0.w += v.w;
        }
        if (j + 1 < c) {
            int s1 = eidx[start + j + 1];
            float4 v = tp4[(size_t)s1 * 16 + sl];
            a1.x += v.x; a1.y += v.y; a1.z += v.z; a1.w += v.w;
        }
    }
    if (j < c) {
        int s0 = eidx[start + j];
        float4 v = tp4[(size_t)s0 * 16 + sl];
        a0.x += v.x; a0.y += v.y; a0.z += v.z; a0.w += v.w;
    }

    const float di = dinv[node];
    const float4 b4 = *(const float4*)(bias + sl * 4);
    float4 r;
    r.x = fmaxf(fmaf(di, a0.x + a1.x, b4.x), 0.0f);
    r.y = fmaxf(fmaf(di, a0.y + a1.y, b4.y), 0.0f);
    r.z = fmaxf(fmaf(di, a0.z + a1.z, b4.z), 0.0f);
    r.w = fmaxf(fmaf(di, a0.w + a1.w, b4.w), 0.0f);
    ((float4*)h)[(size_t)node * 16 + sl] = r;
}

// ---------------- lead attention + pool + linear ----------------
__global__ __launch_bounds__(256) void k_attn(const float* __restrict__ h3,
                                              const float* __restrict__ Wa,
                                              const float* __restrict__ vvec,
                                              const float* __restrict__ Wl,
                                              const float* __restrict__ bl,
                                              float* __restrict__ out,
                                              float* __restrict__ lw) {
    __shared__ float lds_Wl[128 * 32];
    __shared__ float lds_h[4][LEADS * 64];
    __shared__ float lds_p[4][128];
    const int t = threadIdx.x;
    const int lane = t & 63;
    const int wid = t >> 6;

#pragma unroll
    for (int i = 0; i < 16; ++i) lds_Wl[t + i * 256] = Wl[t + i * 256];

    float wa[64];
#pragma unroll
    for (int k = 0; k < 64; ++k) wa[k] = Wa[k * 64 + lane];
    float vl = vvec[lane];
    __syncthreads();

    const int g = blockIdx.x * 4 + wid;

    float hv[LEADS];
#pragma unroll
    for (int r = 0; r < LEADS; ++r) {
        hv[r] = h3[(size_t)(g * LEADS + r) * 64 + lane];
        lds_h[wid][r * 64 + lane] = hv[r];
    }

    float s_[LEADS];
#pragma unroll
    for (int r = 0; r < LEADS; ++r) {
        float acc = 0.0f;
        const float4* h4 = (const float4*)&lds_h[wid][r * 64];
#pragma unroll
        for (int k4 = 0; k4 < 16; ++k4) {
            float4 hb = h4[k4];  // broadcast read
            acc = fmaf(hb.x, wa[4 * k4 + 0], acc);
            acc = fmaf(hb.y, wa[4 * k4 + 1], acc);
            acc = fmaf(hb.z, wa[4 * k4 + 2], acc);
            acc = fmaf(hb.w, wa[4 * k4 + 3], acc);
        }
        float sc = tanhf(acc) * vl;
#pragma unroll
        for (int off = 32; off >= 1; off >>= 1) sc += __shfl_xor(sc, off);
        s_[r] = sc;
    }

    float m = s_[0];
#pragma unroll
    for (int r = 1; r < LEADS; ++r) m = fmaxf(m, s_[r]);
    float wgt[LEADS];
    float sum = 0.0f;
#pragma unroll
    for (int r = 0; r < LEADS; ++r) {
        wgt[r] = expf(s_[r] - m);
        sum += wgt[r];
    }
    float inv = 1.0f / sum;

    float tmp = wgt[0] * inv;
#pragma unroll
    for (int r = 1; r < LEADS; ++r) tmp = (lane == r) ? wgt[r] * inv : tmp;
    if (lane < LEADS) lw[g * LEADS + lane] = tmp;

    float gmax = -1e30f, gsum = 0.0f;
#pragma unroll
    for (int r = 0; r < LEADS; ++r) {
        float wh = hv[r] * (wgt[r] * inv);
        gmax = fmaxf(gmax, wh);
        gsum += wh;
    }
    lds_p[wid][lane] = gmax;
    lds_p[wid][64 + lane] = gsum * (1.0f / 12.0f);

    int o = lane & 31, half = lane >> 5;
    float acc2 = 0.0f;
#pragma unroll
    for (int k = 0; k < 64; ++k) {
        int kk = half * 64 + k;
        acc2 = fmaf(lds_p[wid][kk], lds_Wl[kk * 32 + o], acc2);
    }
    acc2 += __shfl_xor(acc2, 32);
    if (lane < 32) out[g * 32 + lane] = fmaxf(acc2 + bl[lane], 0.0f);
}

// ---------------- launch ----------------
extern "C" void kernel_launch(void* const* d_in, const int* in_sizes, int n_in,
                              void* d_out, int out_size, void* d_ws, size_t ws_size,
                              hipStream_t stream) {
    const float* x  = (const float*)d_in[0];
    const int* ei   = (const int*)d_in[1];
    const int* src  = ei;
    const int* dst  = ei + N_EDGES;
    const float* W1 = (const float*)d_in[3];
    const float* b1 = (const float*)d_in[4];
    const float* W2 = (const float*)d_in[5];
    const float* b2 = (const float*)d_in[6];
    const float* W3 = (const float*)d_in[7];
    const float* b3 = (const float*)d_in[8];
    const float* Wa = (const float*)d_in[9];
    const float* vv = (const float*)d_in[10];
    const float* Wl = (const float*)d_in[11];
    const float* bl = (const float*)d_in[12];

    float* out = (float*)d_out;
    float* lw  = out + (size_t)NUM_GRAPHS * 32;

    float* dinv = (float*)d_ws;                       // N f32
    int* cnt    = (int*)(dinv + N_NODES);             // N
    int* offs   = cnt + N_NODES;                      // N
    int* cursor = offs + N_NODES;                     // N
    int* bsum   = cursor + N_NODES;                   // 1024
    int* eidx   = bsum + 1024;                        // E
    float* T    = (float*)(eidx + N_EDGES);           // N*64
    float* Hb   = T + (size_t)N_NODES * HD;           // N*64

    const int gN = (N_NODES + 255) / 256;
    const int gE = (N_EDGES + 255) / 256;

    k_zero<<<gN, 256, 0, stream>>>(cnt);
    k_hist<<<gE, 256, 0, stream>>>(dst, cnt);
    k_dinv<<<gN, 256, 0, stream>>>(cnt, dinv);
    k_scan1<<<SCAN_BLOCKS, 256, 0, stream>>>(cnt, offs, bsum);
    k_scan2<<<1, 256, 0, stream>>>(bsum);
    k_scan3<<<gN, 256, 0, stream>>>(offs, bsum, cursor);
    k_fill<<<gE, 256, 0, stream>>>(src, dst, cursor, eidx);

    // layer 1
    k_gemm<128><<<N_NODES / 64, 256, 0, stream>>>(x, W1, dinv, T);
    k_gather<<<N_NODES / 16, 256, 0, stream>>>(T, eidx, offs, cnt, dinv, b1, Hb);
    // layer 2
    k_gemm<64><<<N_NODES / 64, 256, 0, stream>>>(Hb, W2, dinv, T);
    k_gather<<<N_NODES / 16, 256, 0, stream>>>(T, eidx, offs, cnt, dinv, b2, Hb);
    // layer 3
    k_gemm<64><<<N_NODES / 64, 256, 0, stream>>>(Hb, W3, dinv, T);
    k_gather<<<N_NODES / 16, 256, 0, stream>>>(T, eidx, offs, cnt, dinv, b3, Hb);
    // attention + pool + linear
    k_attn<<<NUM_GRAPHS / 4, 256, 0, stream>>>(Hb, Wa, vv, Wl, bl, out, lw);
}